// Round 6
// baseline (533.166 us; speedup 1.0000x reference)
//
#include <hip/hip_runtime.h>
#include <math.h>

typedef __bf16 bf16x8 __attribute__((ext_vector_type(8)));
typedef __bf16 bf16x4 __attribute__((ext_vector_type(4)));
typedef float  f32x4  __attribute__((ext_vector_type(4)));

#define MFMA(a,b,c) __builtin_amdgcn_mfma_f32_16x16x32_bf16((a),(b),(c),0,0,0)

#define A_N   128
#define LDIM  256
#define FLATD 4096

// ---------------------------------------------------------------------------
// Repack the 6 latent weight arrays (each [4][256][256] fp32) into split bf16
// (hi + lo) laid out in per-wave consumption order for k_latent.
// COALESCED READS (thread reads 8 contiguous floats), scattered writes.
// Stream layout (bf16 index): (lp*16+w)*49152 + li*512 + lane*8, where
//   li (96 chunks/stream): m<3: ks*6+m*2+hl ; m=3: 48+ks*2+hl ;
//                          m=4: 64+ks*2+hl ; m=5: 80+ks*2+hl
//   chunk(lp,w,li,lane) = W[m][lp][w*16+(lane&15)][ks*32+(lane>>4)*8 + j]
__global__ __launch_bounds__(256) void k_cvt_w(
        const float* __restrict__ s0, const float* __restrict__ s1,
        const float* __restrict__ s2, const float* __restrict__ s3,
        const float* __restrict__ s4, const float* __restrict__ s5,
        __bf16* __restrict__ W) {
    const int gid = blockIdx.x * 256 + threadIdx.x;    // 0..196607
    const int m   = gid >> 15;                         // matrix 0..5
    const int rem = gid & 32767;
    const int off = rem << 3;                          // float offset in matrix
    const int lp  = off >> 16;
    const int win = off & 65535;
    const int row = win >> 8;                          // 0..255
    const int c   = win & 255;                         // col, multiple of 8
    const int w   = row >> 4, lr = row & 15;
    const int ks  = c >> 5,  q  = (c >> 3) & 3;
    const int lane = q * 16 + lr;

    int li_h;
    if (m < 3)       li_h = ks * 6 + m * 2;
    else if (m == 3) li_h = 48 + ks * 2;
    else if (m == 4) li_h = 64 + ks * 2;
    else             li_h = 80 + ks * 2;

    const float* s;
    switch (m) {
        case 0: s = s0; break; case 1: s = s1; break; case 2: s = s2; break;
        case 3: s = s3; break; case 4: s = s4; break; default: s = s5; break;
    }
    const float4* sp = (const float4*)(s + off);
    float4 x = sp[0], y = sp[1];
    float v[8] = {x.x, x.y, x.z, x.w, y.x, y.y, y.z, y.w};
    bf16x8 h, l;
    #pragma unroll
    for (int j = 0; j < 8; ++j) {
        __bf16 hh = (__bf16)v[j];
        h[j] = hh;
        l[j] = (__bf16)(v[j] - (float)hh);
    }
    __bf16* dst = W + (size_t)(lp * 16 + w) * 49152 + (size_t)lane * 8;
    *(bf16x8*)(dst + (size_t)li_h * 512)       = h;
    *(bf16x8*)(dst + (size_t)(li_h + 1) * 512) = l;
}

// ---------------------------------------------------------------------------
// Fused 4-layer latent transformer, split-bf16 (near-fp32) projections.
// One block per asset (16 rows x 256). 1024 threads = 16 waves.
// Weights pre-swizzled (k_cvt_w): wave w reads ONE contiguous 96 KB stream
// per layer, 1 KB per wave-load -- fully coalesced, sequential addresses.
// Final Z is emitted in MFMA-FRAGMENT order (see k_cann_gemm): chunk
// (g*128 + k32) holds Z[g*16 + (lane&15)][k32*32 + (lane>>4)*8 + j] so a
// GEMM wave's A-fragment load is one contiguous 1 KB nt-load.
// MFMA 16x16x32 bf16 layouts (verified m89/m91):
//   A[m=lane&15][k=(lane>>4)*8+j], B[n=lane&15][k=(lane>>4)*8+j]
//   C[m=(lane>>4)*4+reg][n=lane&15]
__global__ __launch_bounds__(1024) void k_latent(
    const float* __restrict__ z,
    const __bf16* __restrict__ Wswz,
    const float* __restrict__ boa,
    const float* __restrict__ g1a, const float* __restrict__ b1a,
    const float* __restrict__ fb1a, const float* __restrict__ fb2a,
    const float* __restrict__ g2a, const float* __restrict__ b2a,
    float* __restrict__ zprior, __bf16* __restrict__ Zsh, __bf16* __restrict__ Zsl)
{
    // LDS arena 57856 B. Aliases (barrier-guarded):
    //   Ph  aliases zbh (zb dead between qkv-proj and LN1)
    //   ob  aliases Qh + first 256 B of Kh (dead after scores)
    __shared__ __align__(16) char arena[57856];
    float*  zf  = (float*)arena;                    // [16][256] f32 residual
    __bf16* zbh = (__bf16*)(arena + 16384);         // [16][264]
    __bf16* zbl = (__bf16*)(arena + 24832);         // [16][264]
    __bf16* Ph  = (__bf16*)(arena + 16384);         // [8][16][32] (k-pad 0)
    __bf16* Qh  = (__bf16*)(arena + 33280);         // [8][16][32]
    __bf16* ob  = Qh;                               // [16][264]
    __bf16* Kh  = (__bf16*)(arena + 41472);         // [8][16][32]
    __bf16* Vt  = (__bf16*)(arena + 49664);         // [8][32][16] V^T compact

    const int a    = blockIdx.x;
    const int t    = threadIdx.x;
    const int w    = t >> 6;          // 0..15
    const int lane = t & 63;
    const int q    = lane >> 4;
    const int r    = lane & 15;
    const int nc   = w * 16;          // GEMM output col base for this wave
    const int head = w >> 1;          // attention head for qkv store
    const int hc   = (w & 1) * 16;    // col-half within head

    // ---- load z -> zf, zbh/zbl; emit z_prior (4 floats/thread) ----
    {
        int row = t >> 6, col = (t & 63) * 4;
        const float4 x = *(const float4*)(z + (size_t)a * 4096 + row * 256 + col);
        *(float4*)(zprior + (size_t)a * 4096 + row * 256 + col) = x;
        float v[4] = {x.x, x.y, x.z, x.w};
        float*  zr = zf  + row * 256 + col;
        __bf16* zh = zbh + row * 264 + col;
        __bf16* zl = zbl + row * 264 + col;
        #pragma unroll
        for (int j = 0; j < 4; ++j) {
            zr[j] = v[j];
            __bf16 hh = (__bf16)v[j];
            zh[j] = hh;
            zl[j] = (__bf16)(v[j] - (float)hh);
        }
    }
    __syncthreads();

    // wave w handles row w (64 lanes x 4 cols)
    auto do_ln = [&](const float* g, const float* bb) {
        int col = lane * 4;
        float* zr = zf + w * 256 + col;
        float4 v4 = *(const float4*)zr;
        float v[4] = {v4.x, v4.y, v4.z, v4.w};
        float s1 = 0.f, s2 = 0.f;
        #pragma unroll
        for (int j = 0; j < 4; ++j) { s1 += v[j]; s2 += v[j]*v[j]; }
        #pragma unroll
        for (int o = 1; o <= 32; o <<= 1) {
            s1 += __shfl_xor(s1, o);
            s2 += __shfl_xor(s2, o);
        }
        float mean = s1 * (1.0f/256.0f);
        float var  = s2 * (1.0f/256.0f) - mean * mean;
        float inv  = rsqrtf(var + 1e-5f);
        float4 g4 = *(const float4*)(g + col);
        float4 b4 = *(const float4*)(bb + col);
        float gg[4] = {g4.x, g4.y, g4.z, g4.w};
        float bbv[4] = {b4.x, b4.y, b4.z, b4.w};
        __bf16* zh = zbh + w * 264 + col;
        __bf16* zl = zbl + w * 264 + col;
        float y[4];
        #pragma unroll
        for (int j = 0; j < 4; ++j) {
            y[j] = (v[j] - mean) * inv * gg[j] + bbv[j];
            __bf16 hh = (__bf16)y[j];
            zh[j] = hh;
            zl[j] = (__bf16)(y[j] - (float)hh);
        }
        *(float4*)zr = (float4){y[0], y[1], y[2], y[3]};
    };

    const f32x4 zero4 = {0.f, 0.f, 0.f, 0.f};
    bf16x8 zer8;
    #pragma unroll
    for (int j = 0; j < 8; ++j) zer8[j] = (__bf16)0.0f;

    for (int lp = 0; lp < 4; ++lp) {
        const float* bo  = boa  + lp*256;
        const float* g1  = g1a  + lp*256; const float* b1 = b1a + lp*256;
        const float* fb1 = fb1a + lp*256; const float* fb2 = fb2a + lp*256;
        const float* g2  = g2a  + lp*256; const float* b2 = b2a + lp*256;

        // per-wave contiguous weight stream (see k_cvt_w layout comment)
        const __bf16* wsl = Wswz + (size_t)(lp * 16 + w) * 49152 + (size_t)lane * 8;
        #define WCHUNK(idx) (*(const bf16x8*)(wsl + (idx) * 512))

        const __bf16* zA_h = zbh + r * 264 + q * 8;          // A frag base
        const __bf16* zA_l = zbl + r * 264 + q * 8;
        const __bf16* oA   = ob  + r * 264 + q * 8;

        // ---- q,k,v projections: 3 interleaved split-product chains ----
        {
            f32x4 aq = zero4, ak = zero4, av = zero4;
            #pragma unroll
            for (int ks = 0; ks < 8; ++ks) {
                bf16x8 afh = *(const bf16x8*)(zA_h + ks*32);
                bf16x8 afl = *(const bf16x8*)(zA_l + ks*32);
                bf16x8 qh = WCHUNK(ks*6 + 0);
                bf16x8 ql = WCHUNK(ks*6 + 1);
                bf16x8 kh = WCHUNK(ks*6 + 2);
                bf16x8 kl = WCHUNK(ks*6 + 3);
                bf16x8 vh = WCHUNK(ks*6 + 4);
                bf16x8 vl = WCHUNK(ks*6 + 5);
                aq = MFMA(afh, qh, aq); aq = MFMA(afl, qh, aq); aq = MFMA(afh, ql, aq);
                ak = MFMA(afh, kh, ak); ak = MFMA(afl, kh, ak); ak = MFMA(afh, kl, ak);
                av = MFMA(afh, vh, av); av = MFMA(afl, vh, av); av = MFMA(afh, vl, av);
            }
            #pragma unroll
            for (int i = 0; i < 4; ++i) {
                int m = q*4 + i;
                Qh[(head*16 + m)*32 + hc + r] = (__bf16)aq[i];
                Kh[(head*16 + m)*32 + hc + r] = (__bf16)ak[i];
                Vt[(head*32 + hc + r)*16 + m] = (__bf16)av[i];
            }
        }
        __syncthreads();   // Qh/Kh/Vt visible; zb reads done (Ph may alias)

        // ---- scores + softmax, head w per wave (waves 0..7 only) ----
        if (w < 8) {
            bf16x8 qa = *(const bf16x8*)(Qh + (w*16 + r)*32 + q*8);
            bf16x8 ka = *(const bf16x8*)(Kh + (w*16 + r)*32 + q*8);
            f32x4 s = MFMA(qa, ka, zero4);   // S[i=q*4+reg][j=r], K = hd = 32
            #pragma unroll
            for (int i = 0; i < 4; ++i) {
                float sc = s[i] * 0.17677669529663687f;
                float mx = sc;
                #pragma unroll
                for (int o = 1; o <= 8; o <<= 1) mx = fmaxf(mx, __shfl_xor(mx, o, 16));
                float e = __expf(sc - mx);
                float sm = e;
                #pragma unroll
                for (int o = 1; o <= 8; o <<= 1) sm += __shfl_xor(sm, o, 16);
                Ph[(w*16 + q*4 + i)*32 + r]      = (__bf16)(e / sm);
                Ph[(w*16 + q*4 + i)*32 + 16 + r] = (__bf16)0.0f;   // k-pad
            }
        }
        __syncthreads();   // all Qh/Kh reads done (ob may alias)

        // ---- O = P @ V. 16 waves: head = w&7, d-half = w>>3 ----
        {
            int ph = w & 7, vnt = w >> 3;
            bf16x8 pa = *(const bf16x8*)(Ph + (ph*16 + r)*32 + q*8);
            bf16x8 vb = (q < 2)
                ? *(const bf16x8*)(Vt + (ph*32 + vnt*16 + r)*16 + q*8) : zer8;
            f32x4 o = MFMA(pa, vb, zero4);   // O[i=q*4+reg][d=nt*16+r]
            #pragma unroll
            for (int i = 0; i < 4; ++i)
                ob[(q*4 + i)*264 + ph*32 + vnt*16 + r] = (__bf16)o[i];
        }
        __syncthreads();

        // ---- wo projection (A=ob single, split B) + bias + residual ----
        {
            f32x4 acc = zero4;
            #pragma unroll
            for (int ks = 0; ks < 8; ++ks) {
                bf16x8 af = *(const bf16x8*)(oA + ks*32);
                bf16x8 bh = WCHUNK(48 + ks*2);
                bf16x8 bl = WCHUNK(49 + ks*2);
                acc = MFMA(af, bh, acc);
                acc = MFMA(af, bl, acc);
            }
            #pragma unroll
            for (int i = 0; i < 4; ++i) {
                int row = q*4 + i, col = nc + r;
                zf[row*256 + col] = acc[i] + bo[col] + zf[row*256 + col];
            }
        }
        __syncthreads();
        do_ln(g1, b1);
        __syncthreads();

        // ---- FF1: relu(z @ f1^T + fb1) -> ob (split A x split B) ----
        {
            f32x4 acc = zero4;
            #pragma unroll
            for (int ks = 0; ks < 8; ++ks) {
                bf16x8 afh = *(const bf16x8*)(zA_h + ks*32);
                bf16x8 afl = *(const bf16x8*)(zA_l + ks*32);
                bf16x8 bh  = WCHUNK(64 + ks*2);
                bf16x8 bl  = WCHUNK(65 + ks*2);
                acc = MFMA(afh, bh, acc);
                acc = MFMA(afl, bh, acc);
                acc = MFMA(afh, bl, acc);
            }
            #pragma unroll
            for (int i = 0; i < 4; ++i) {
                int row = q*4 + i, col = nc + r;
                ob[row*264 + col] = (__bf16)fmaxf(acc[i] + fb1[col], 0.0f);
            }
        }
        __syncthreads();

        // ---- FF2 (A=ob single, split B) + bias + residual ----
        {
            f32x4 acc = zero4;
            #pragma unroll
            for (int ks = 0; ks < 8; ++ks) {
                bf16x8 af = *(const bf16x8*)(oA + ks*32);
                bf16x8 bh = WCHUNK(80 + ks*2);
                bf16x8 bl = WCHUNK(81 + ks*2);
                acc = MFMA(af, bh, acc);
                acc = MFMA(af, bl, acc);
            }
            #pragma unroll
            for (int i = 0; i < 4; ++i) {
                int row = q*4 + i, col = nc + r;
                zf[row*256 + col] = acc[i] + fb2[col] + zf[row*256 + col];
            }
        }
        __syncthreads();
        do_ln(g2, b2);
        __syncthreads();
        #undef WCHUNK
    }

    // ---- emit final z in MFMA-fragment order for the CANN GEMM ----
    // chunk (g*128 + k32): lane (q*16+r) elem j = Z[g*16+r][k32*32+q*8+j].
    // Block a contributes r = a&15 of g = a>>4: thread t<512 covers k = t*8.
    if (t < 512) {
        int srow = t >> 5, scol = (t & 31) * 8;      // source k = t*8
        size_t dest = ((size_t)((a >> 4) * 128 + (t >> 2)) << 9)
                    + (size_t)(((t & 3) * 16 + (a & 15)) * 8);
        *(bf16x8*)(Zsh + dest) = *(const bf16x8*)(zbh + srow * 264 + scol);
        *(bf16x8*)(Zsl + dest) = *(const bf16x8*)(zbl + srow * 264 + scol);
    }
}

// ---------------------------------------------------------------------------
// CANN q/k/v GEMM, split-bf16: C[128,4096] = Z @ W^T + b, near-fp32 accuracy.
// BM=128, BN=64, BK=64. grid (64, 3) x 512 (8 waves, 1 block/CU, 192 blocks).
// v4: A (Z) is NOT staged in LDS. Z comes pre-swizzled in MFMA-fragment
// order (see k_latent emit): each wave's A-fragment = one contiguous 1 KB
// nt-load straight into registers. This cuts LDS traffic 177->80 KB/iter
// (the round-5 bottleneck) and shrinks the barrier path to the 16 KB
// B-stage. W issues BEFORE A in each stage so wrB's auto-vmcnt (which waits
// the oldest W pair) leaves the A prefetch in flight.
// Double-buffered B LDS, 2-deep prefetch, ONE raw s_barrier per K-step,
// no vmcnt drain. MFMA order per accumulator unchanged (bit-identical).
// y==1 (K) stored transposed (KT[4096][128]) for k_cann_scores.
__global__ __launch_bounds__(512) void k_cann_gemm(
    const __bf16* __restrict__ Zsh, const __bf16* __restrict__ Zsl,
    const float* __restrict__ W0, const float* __restrict__ W1, const float* __restrict__ W2,
    const float* __restrict__ b0, const float* __restrict__ b1, const float* __restrict__ b2,
    float* __restrict__ C0, float* __restrict__ C1, float* __restrict__ C2)
{
    const float* W; const float* bias; float* C;
    if (blockIdx.y == 0)      { W = W0; bias = b0; C = C0; }
    else if (blockIdx.y == 1) { W = W1; bias = b1; C = C1; }
    else                      { W = W2; bias = b2; C = C2; }

    __shared__ __bf16 BshB[2][64 * 72];
    __shared__ __bf16 BslB[2][64 * 72];

    const int t = threadIdx.x;
    const int w = t >> 6, lane = t & 63, q = lane >> 4, r = lane & 15;
    const int n0 = blockIdx.x * 64;
    const int m0 = (w >> 1) * 32;     // wave's M base (4 M-quadrants)
    const int nw = (w & 1) * 32;      // wave's N base within block (2 halves)
    const int g0 = (w >> 1) * 2;      // A fragment m-group base (16-row groups)
    const int br = t >> 3, bc = (t & 7) * 8;   // B staging: 64 rows x 8 fp32

    // ---- register stages (explicit names; no runtime-indexed arrays) ----
    bf16x8 Ah0[2][2], Al0[2][2];   // stage 0: [gi][ks]
    bf16x8 Ah1[2][2], Al1[2][2];   // stage 1
    f32x4  Wx0, Wy0, Wx1, Wy1;

    // W first, then A: wrB's vmcnt wait (oldest W) leaves A in flight.
    auto issue = [&](bf16x8 (&Ah)[2][2], bf16x8 (&Al)[2][2],
                     f32x4& Wx, f32x4& Wy, int tile) {
        const f32x4* wp = (const f32x4*)(W + (size_t)(n0 + br) * FLATD
                                           + tile * 64 + bc);
        Wx = __builtin_nontemporal_load(wp);
        Wy = __builtin_nontemporal_load(wp + 1);
        #pragma unroll
        for (int gi = 0; gi < 2; ++gi)
            #pragma unroll
            for (int ks = 0; ks < 2; ++ks) {
                size_t off = ((size_t)((g0 + gi) * 128 + tile * 2 + ks) << 9)
                           + (size_t)(lane * 8);
                Ah[gi][ks] = __builtin_nontemporal_load((const bf16x8*)(Zsh + off));
                Al[gi][ks] = __builtin_nontemporal_load((const bf16x8*)(Zsl + off));
            }
    };

    auto wrB = [&](const f32x4& Wx, const f32x4& Wy, int b) {
        float v[8] = {Wx[0], Wx[1], Wx[2], Wx[3], Wy[0], Wy[1], Wy[2], Wy[3]};
        bf16x8 h, l;
        #pragma unroll
        for (int j = 0; j < 8; ++j) {
            __bf16 hh = (__bf16)v[j];
            h[j] = hh;
            l[j] = (__bf16)(v[j] - (float)hh);
        }
        *(bf16x8*)(&BshB[b][br * 72 + bc]) = h;
        *(bf16x8*)(&BslB[b][br * 72 + bc]) = l;
    };

    const f32x4 zero4 = {0.f, 0.f, 0.f, 0.f};
    f32x4 acc[2][2] = {{zero4, zero4}, {zero4, zero4}};

    auto mfma_phase = [&](const bf16x8 (&Ah)[2][2], const bf16x8 (&Al)[2][2],
                          int b) {
        #pragma unroll
        for (int ks = 0; ks < 2; ++ks) {
            bf16x8 g0h = *(const bf16x8*)(&BshB[b][(nw + r)      * 72 + ks*32 + q*8]);
            bf16x8 g1h = *(const bf16x8*)(&BshB[b][(nw + 16 + r) * 72 + ks*32 + q*8]);
            bf16x8 g0l = *(const bf16x8*)(&BslB[b][(nw + r)      * 72 + ks*32 + q*8]);
            bf16x8 g1l = *(const bf16x8*)(&BslB[b][(nw + 16 + r) * 72 + ks*32 + q*8]);
            acc[0][0] = MFMA(Ah[0][ks], g0h, acc[0][0]);
            acc[0][0] = MFMA(Al[0][ks], g0h, acc[0][0]);
            acc[0][0] = MFMA(Ah[0][ks], g0l, acc[0][0]);
            acc[0][1] = MFMA(Ah[0][ks], g1h, acc[0][1]);
            acc[0][1] = MFMA(Al[0][ks], g1h, acc[0][1]);
            acc[0][1] = MFMA(Ah[0][ks], g1l, acc[0][1]);
            acc[1][0] = MFMA(Ah[1][ks], g0h, acc[1][0]);
            acc[1][0] = MFMA(Al[1][ks], g0h, acc[1][0]);
            acc[1][0] = MFMA(Ah[1][ks], g0l, acc[1][0]);
            acc[1][1] = MFMA(Ah[1][ks], g1h, acc[1][1]);
            acc[1][1] = MFMA(Al[1][ks], g1h, acc[1][1]);
            acc[1][1] = MFMA(Ah[1][ks], g1l, acc[1][1]);
        }
    };

    #define LGKM0_BAR() do {                                      \
        asm volatile("s_waitcnt lgkmcnt(0)" ::: "memory");        \
        __builtin_amdgcn_sched_barrier(0);                        \
        __builtin_amdgcn_s_barrier();                             \
        __builtin_amdgcn_sched_barrier(0);                        \
    } while (0)

    // prologue: tiles 0,1 in flight; B of tile 0 -> buf 0
    issue(Ah0, Al0, Wx0, Wy0, 0);
    issue(Ah1, Al1, Wx1, Wy1, 1);
    wrB(Wx0, Wy0, 0);
    LGKM0_BAR();

    for (int it = 0; it < 31; ++it) {
        // even step: tile 2it (stage 0 / buf 0)
        mfma_phase(Ah0, Al0, 0);
        issue(Ah0, Al0, Wx0, Wy0, 2*it + 2);
        wrB(Wx1, Wy1, 1);
        LGKM0_BAR();
        // odd step: tile 2it+1 (stage 1 / buf 1)
        mfma_phase(Ah1, Al1, 1);
        issue(Ah1, Al1, Wx1, Wy1, 2*it + 3);
        wrB(Wx0, Wy0, 0);
        LGKM0_BAR();
    }
    // tile 62
    mfma_phase(Ah0, Al0, 0);
    wrB(Wx1, Wy1, 1);
    LGKM0_BAR();
    // tile 63
    mfma_phase(Ah1, Al1, 1);
    #undef LGKM0_BAR

    if (blockIdx.y == 1) {
        // KT[col][row] = acc + bias[col]
        #pragma unroll
        for (int mi = 0; mi < 2; ++mi)
            #pragma unroll
            for (int ni = 0; ni < 2; ++ni)
                #pragma unroll
                for (int i = 0; i < 4; ++i) {
                    int row = m0 + mi*16 + q*4 + i;
                    int col = n0 + nw + ni*16 + r;
                    C[(size_t)col * 128 + row] = acc[mi][ni][i] + bias[col];
                }
    } else {
        #pragma unroll
        for (int mi = 0; mi < 2; ++mi)
            #pragma unroll
            for (int ni = 0; ni < 2; ++ni)
                #pragma unroll
                for (int i = 0; i < 4; ++i) {
                    int row = m0 + mi*16 + q*4 + i;
                    int col = n0 + nw + ni*16 + r;
                    C[(size_t)row * FLATD + col] = acc[mi][ni][i] + bias[col];
                }
    }
}

// ---------------------------------------------------------------------------
// CANN scores + softmax, 2 Q-rows per block (amortizes the KT stream):
// P[i][j] = softmax_j(Q[i]·K[j] / 16). KT is [4096][128] (k-major).
// 512 threads: j = t&127, 4-way k-split (t>>7). Q rows staged in LDS.
__global__ __launch_bounds__(512) void k_cann_scores(const float* __restrict__ Q,
                              const float* __restrict__ KT,
                              float* __restrict__ P) {
    const int i0 = blockIdx.x * 2;
    const int t  = threadIdx.x;
    __shared__ float qs[2][FLATD];
    __shared__ float part[4][2][128];
    __shared__ float wred[2][2];
    __shared__ float wsum[2][2];
    {
        const float4* src = (const float4*)(Q + (size_t)i0 * FLATD);
        float4* dst = (float4*)qs;
        #pragma unroll
        for (int u = 0; u < 4; ++u) dst[t + u * 512] = src[t + u * 512];
    }
    __syncthreads();

    const int j = t & 127, ksub = t >> 7;
    const float* kp = KT + (size_t)(ksub * 1024) * 128 + j;
    const float* q0 = qs[0] + ksub * 1024;
    const float* q1 = qs[1] + ksub * 1024;
    float a0 = 0.0f, a1 = 0.0f;
    #pragma unroll 8
    for (int k = 0; k < 1024; ++k) {
        float kv = kp[(size_t)k * 128];
        a0 += q0[k] * kv;
        a1 += q1[k] * kv;
    }
    part[ksub][0][j] = a0;
    part[ksub][1][j] = a1;
    __syncthreads();

    // t < 256: i = t>>7, j = t&127; softmax per row across 2 waves
    float v = 0.0f, e = 0.0f;
    const int i = t >> 7;
    if (t < 256)
        v = (part[0][i][j] + part[1][i][j] + part[2][i][j] + part[3][i][j]) * 0.0625f;

    float mx = (t < 256) ? v : -3.4e38f;
    #pragma unroll
    for (int o = 32; o; o >>= 1) mx = fmaxf(mx, __shfl_xor(mx, o));
    if (t < 256 && (j & 63) == 0) wred[i][j >> 6] = mx;
    __syncthreads();
    if (t < 256) {
        mx = fmaxf(wred[i][0], wred[i][1]);
        e = __expf(v - mx);
    }
    float sum = e;
    #pragma unroll
    for (int o = 32; o; o >>= 1) sum += __shfl_xor(sum, o);
    if (t < 256 && (j & 63) == 0) wsum[i][j >> 6] = sum;
    __syncthreads();
    if (t < 256) {
        sum = wsum[i][0] + wsum[i][1];
        P[(size_t)(i0 + i) * 128 + j] = e / sum;
    }
}

// ---------------------------------------------------------------------------
// H[i][n] = sum_j P[i][j] * V[j][n]. 8 rows x 1024-col tile per block:
// V traffic 268 MB -> 32 MB. P staged transposed (ps[j][i]) for b128 reads.
__global__ __launch_bounds__(256) void k_cann_out(const float* __restrict__ P,
                           const float* __restrict__ V,
                           float* __restrict__ H) {
    const int i0 = blockIdx.y * 8;
    const int t  = threadIdx.x;
    const int nb = blockIdx.x * 1024 + t * 4;
    __shared__ float ps[128][8];
    #pragma unroll
    for (int u = 0; u < 4; ++u) {
        int e = t + u * 256;            // 0..1023
        int i = e >> 7, j = e & 127;
        ps[j][i] = P[(size_t)(i0 + i) * 128 + j];
    }
    __syncthreads();

    f32x4 acc[8];
    #pragma unroll
    for (int i = 0; i < 8; ++i) acc[i] = (f32x4){0.f, 0.f, 0.f, 0.f};

    for (int j = 0; j < 128; ++j) {
        float4 vv = *(const float4*)(V + (size_t)j * FLATD + nb);
        f32x4 v4 = {vv.x, vv.y, vv.z, vv.w};
        float4 pa = *(const float4*)&ps[j][0];
        float4 pb = *(const float4*)&ps[j][4];
        acc[0] += pa.x * v4; acc[1] += pa.y * v4;
        acc[2] += pa.z * v4; acc[3] += pa.w * v4;
        acc[4] += pb.x * v4; acc[5] += pb.y * v4;
        acc[6] += pb.z * v4; acc[7] += pb.w * v4;
    }
    #pragma unroll
    for (int i = 0; i < 8; ++i) {
        f32x4 a = acc[i];
        *(float4*)(H + (size_t)(i0 + i) * FLATD + nb) =
            (float4){a[0], a[1], a[2], a[3]};
    }
}

// ---------------------------------------------------------------------------
extern "C" void kernel_launch(void* const* d_in, const int* in_sizes, int n_in,
                              void* d_out, int out_size, void* d_ws, size_t ws_size,
                              hipStream_t stream) {
    (void)in_sizes; (void)n_in; (void)out_size; (void)ws_size;

    const float* z      = (const float*)d_in[1];
    const float* s_wq   = (const float*)d_in[15];
    const float* s_wk   = (const float*)d_in[16];
    const float* s_wv   = (const float*)d_in[17];
    const float* s_wo   = (const float*)d_in[18];
    const float* s_bo   = (const float*)d_in[19];
    const float* s_ln1g = (const float*)d_in[20];
    const float* s_ln1b = (const float*)d_in[21];
    const float* s_fw1  = (const float*)d_in[22];
    const float* s_fb1  = (const float*)d_in[23];
    const float* s_fw2  = (const float*)d_in[24];
    const float* s_fb2  = (const float*)d_in[25];
    const float* s_ln2g = (const float*)d_in[26];
    const float* s_ln2b = (const float*)d_in[27];
    const float* q_w    = (const float*)d_in[28];
    const float* q_b    = (const float*)d_in[29];
    const float* k_w    = (const float*)d_in[30];
    const float* k_b    = (const float*)d_in[31];
    const float* v_w    = (const float*)d_in[32];
    const float* v_b    = (const float*)d_in[33];

    float* out    = (float*)d_out;
    float* Hout   = out;
    float* Zprior = out + 524288;

    // Workspace: [0,6MB) = Wswz, later reused as Qb/KT/Vb (Wswz dead by then)
    char* w8 = (char*)d_ws;
    __bf16* Wswz = (__bf16*)w8;                    // 6.29 MB swizzled weights
    float*  Qb  = (float*)w8;                      // 2 MB (aliases Wswz)
    float*  Kb  = (float*)(w8 + 2097152);          // 2 MB (KT[4096][128])
    float*  Vb  = (float*)(w8 + 4194304);          // 2 MB
    __bf16* Zsh = (__bf16*)(w8 + 6291456);         // 1 MB (fragment-order Z hi)
    __bf16* Zsl = (__bf16*)(w8 + 7340032);         // 1 MB (fragment-order Z lo)
    float*  Pm  = (float*)(w8 + 8388608);          // 64 KB

    k_cvt_w<<<768, 256, 0, stream>>>(s_wq, s_wk, s_wv, s_wo, s_fw1, s_fw2, Wswz);

    k_latent<<<A_N, 1024, 0, stream>>>(z, Wswz, s_bo, s_ln1g, s_ln1b,
                                       s_fb1, s_fb2, s_ln2g, s_ln2b,
                                       Zprior, Zsh, Zsl);

    k_cann_gemm<<<dim3(FLATD / 64, 3), 512, 0, stream>>>(Zsh, Zsl, q_w, k_w, v_w,
                                                         q_b, k_b, v_b, Qb, Kb, Vb);

    k_cann_scores<<<A_N / 2, 512, 0, stream>>>(Qb, Kb, Pm);
    k_cann_out<<<dim3(4, 16), 256, 0, stream>>>(Pm, Vb, Hout);
}